// Round 2
// baseline (133.901 us; speedup 1.0000x reference)
//
#include <hip/hip_runtime.h>
#include <hip/hip_bf16.h>

typedef __attribute__((ext_vector_type(8)))  __bf16 bf16x8;
typedef __attribute__((ext_vector_type(16))) float  f32x16;

#define N_TILES   72          // 2304 / 32
#define W2F_ELEMS (72*4*64*8) // 147456 bf16
#define W1F_ELEMS (2*4*64*8)  // 4096 bf16

// ---------------- prep: pack W2^T/8 and W1^T/8 (bf16) in MFMA A-fragment order ----------------
// A-frag order: [tile][ks][lane][j] holds A[row = 32*tile + (lane&31)][k = 16*ks + 8*(lane>>5) + j]
__global__ __launch_bounds__(256) void equiconv_prep(const float* __restrict__ W1,
                                                     const float* __restrict__ W2,
                                                     __bf16* __restrict__ W1F,
                                                     __bf16* __restrict__ W2F) {
    int idx = blockIdx.x * 256 + threadIdx.x;
    if (idx < W2F_ELEMS) {
        int j  = idx & 7;
        int ln = (idx >> 3) & 63;
        int ks = (idx >> 9) & 3;
        int t  = idx >> 11;
        int m  = 32 * t + (ln & 31);          // W2 column (0..2303)
        int c  = ks * 16 + 8 * (ln >> 5) + j; // W2 row    (0..63)
        W2F[idx] = (__bf16)(W2[c * 2304 + m] * 0.125f);
    } else {
        int i2 = idx - W2F_ELEMS;
        if (i2 < W1F_ELEMS) {
            int j  = i2 & 7;
            int ln = (i2 >> 3) & 63;
            int ks = (i2 >> 9) & 3;
            int mt = i2 >> 11;
            int c  = 32 * mt + (ln & 31);      // W1 output col (0..63)
            int in = ks * 16 + 8 * (ln >> 5) + j;
            W1F[i2] = (__bf16)(W1[in * 64 + c] * 0.125f);
        }
    }
}

// ---------------- main fused kernel: 128 elements / block (4 waves x 32 elems) ----------------
// LDS float layout (16896 floats = 67584 B):
//   [0     .. 4096 )  X10[u=32][e=128]      raw x1_0
//   [4096  .. 6144 )  CB1[u=16][e=128]      pre-scaled sum_i x1_1*x2_1
//   [6144  .. 12288)  X11[i=3][u=16][e=128] raw x1_1
//   [12288 .. 12800)  F2 [e=128][4]
//   [12800 .. 16896)  HT  (bf16[128][64], XOR-swizzled)   -- 8192 bf16
// Output staging (after main loop) reuses [0 .. 10240) floats.
#define X10f(u, el)    smemf[(u)*128 + (el)]
#define CB1f(u, el)    smemf[4096 + (u)*128 + (el)]
#define X11f(k, u, el) smemf[6144 + ((k)*16 + (u))*128 + (el)]
#define F2f(el, j)     smemf[12288 + (el)*4 + (j)]

__global__ __launch_bounds__(256) void equiconv_main(const float* __restrict__ fea_in1,
                                                     const float* __restrict__ fea_in2,
                                                     const float* __restrict__ fea_w,
                                                     const __bf16* __restrict__ W2F,
                                                     const __bf16* __restrict__ W1F,
                                                     float* __restrict__ out) {
    __shared__ __align__(16) float smemf[16896];
    __bf16* HT = (__bf16*)(smemf + 12800);

    const int tid  = threadIdx.x;
    const int lane = tid & 63;
    const int wv   = tid >> 6;     // wave 0..3
    const int l31  = lane & 31;
    const int hi   = lane >> 5;    // half-wave
    const int eBlk = blockIdx.x * 128;
    const int eLoc = wv * 32 + l31;       // element owned by this lane (0..127)
    const int sw   = (eLoc & 7) << 3;     // XOR swizzle (element units) for HT

    // ---- stage fea_in1 -> X10/X11, fea_in2 -> F2 (coalesced global reads) ----
    for (int i = tid; i < 128 * 80; i += 256) {
        float v = fea_in1[(size_t)eBlk * 80 + i];
        int el = i / 80;
        int j  = i - el * 80;
        if (j < 32) {
            X10f(j, el) = v;
        } else {
            int jj = j - 32;
            int u  = jj / 3;
            int k  = jj - u * 3;
            X11f(k, u, el) = v;
        }
    }
    for (int i = tid; i < 128 * 4; i += 256)
        F2f(i >> 2, i & 3) = fea_in2[(size_t)eBlk * 4 + i];
    __syncthreads();

    // ---- CB1[u][e] = sqrt(1/96) * sum_i x1_1[e][u][i]*x2_1[e][i] ----
    const float c110 = 0.10206207261596577f; // sqrt(1/96) = pw110*ISQRT3
    for (int i = tid; i < 16 * 128; i += 256) {
        int u = i >> 7, el = i & 127;
        CB1f(u, el) = c110 * (X11f(0, u, el) * F2f(el, 1) +
                              X11f(1, u, el) * F2f(el, 2) +
                              X11f(2, u, el) * F2f(el, 3));
    }

    // ---- GEMM1: x[c][e] = sum_in (W1[in][c]/8) * feaw[e][in]; h = 1.679*silu(x) ----
    const f32x16 Z16 = {0,0,0,0,0,0,0,0,0,0,0,0,0,0,0,0};
    {
        bf16x8 bw[4];
        const float* pw = fea_w + (size_t)(eBlk + eLoc) * 64 + hi * 8;
#pragma unroll
        for (int ks = 0; ks < 4; ++ks) {
            float4 u0 = *(const float4*)(pw + ks * 16);
            float4 u1 = *(const float4*)(pw + ks * 16 + 4);
            bf16x8 b;
            b[0] = (__bf16)u0.x; b[1] = (__bf16)u0.y; b[2] = (__bf16)u0.z; b[3] = (__bf16)u0.w;
            b[4] = (__bf16)u1.x; b[5] = (__bf16)u1.y; b[6] = (__bf16)u1.z; b[7] = (__bf16)u1.w;
            bw[ks] = b;
        }
        f32x16 h0 = Z16, h1 = Z16;
#pragma unroll
        for (int ks = 0; ks < 4; ++ks) {
            bf16x8 a0 = *(const bf16x8*)(W1F + (size_t)((0 * 4 + ks) * 64 + lane) * 8);
            h0 = __builtin_amdgcn_mfma_f32_32x32x16_bf16(a0, bw[ks], h0, 0, 0, 0);
            bf16x8 a1 = *(const bf16x8*)(W1F + (size_t)((1 * 4 + ks) * 64 + lane) * 8);
            h1 = __builtin_amdgcn_mfma_f32_32x32x16_bf16(a1, bw[ks], h1, 0, 0, 0);
        }
#pragma unroll
        for (int r = 0; r < 16; ++r) {
            int rv = (r & 3) + 8 * (r >> 2) + 4 * hi;
            float x0 = h0[r];
            HT[eLoc * 64 + (rv ^ sw)]        = (__bf16)(1.679f * x0 / (1.f + expf(-x0)));
            float x1 = h1[r];
            HT[eLoc * 64 + ((32 + rv) ^ sw)] = (__bf16)(1.679f * x1 / (1.f + expf(-x1)));
        }
    }
    __syncthreads();

    // ---- per-lane state for main loop ----
    const float x20  = F2f(eLoc, 0);
    const float x21a = F2f(eLoc, 1), x21b = F2f(eLoc, 2), x21c = F2f(eLoc, 3);
    const float sA0  = 0.125f * x20;                 // pw00 * x2_0
    const float s101 = 0.17677669529663687f * x20;   // sqrt(1/32) * x2_0

    bf16x8 hfr[4];
#pragma unroll
    for (int ks = 0; ks < 4; ++ks)
        hfr[ks] = *(const bf16x8*)&HT[eLoc * 64 + ((ks * 16 + 8 * hi) ^ sw)];

    float acc0[16];
    float t011[8];
    float t101[3][8];
#pragma unroll
    for (int r = 0; r < 16; ++r) acc0[r] = 0.f;
#pragma unroll
    for (int s = 0; s < 8; ++s) { t011[s] = 0.f; t101[0][s] = 0.f; t101[1][s] = 0.f; t101[2][s] = 0.f; }

    const __bf16* const pW2l = W2F + (size_t)lane * 8;

#define LOADA(dst, T) {                                                   \
        dst[0] = *(const bf16x8*)(pW2l + (size_t)((T) * 4 + 0) * 512);    \
        dst[1] = *(const bf16x8*)(pW2l + (size_t)((T) * 4 + 1) * 512);    \
        dst[2] = *(const bf16x8*)(pW2l + (size_t)((T) * 4 + 2) * 512);    \
        dst[3] = *(const bf16x8*)(pW2l + (size_t)((T) * 4 + 3) * 512); }

#define MFMA_T(Cv, Af) {                                                          \
        Cv = __builtin_amdgcn_mfma_f32_32x32x16_bf16(Af[0], hfr[0], Z16, 0,0,0);  \
        Cv = __builtin_amdgcn_mfma_f32_32x32x16_bf16(Af[1], hfr[1], Cv,  0,0,0);  \
        Cv = __builtin_amdgcn_mfma_f32_32x32x16_bf16(Af[2], hfr[2], Cv,  0,0,0);  \
        Cv = __builtin_amdgcn_mfma_f32_32x32x16_bf16(Af[3], hfr[3], Cv,  0,0,0); }

    // epilogues: C row rv=(r&3)+8*(r>>2)+4*hi; w_out = rv&15 -> slot s = r&7; u-select = (rv>=16) = (r>=8)
#define EPI_W00(TT) { float cf = sA0 * X10f((TT), eLoc);                          \
        _Pragma("unroll") for (int r = 0; r < 16; ++r) acc0[r] += cf * Cv[r]; }
#define EPI_W110(TT) { float cf = CB1f((TT) - 32, eLoc);                          \
        _Pragma("unroll") for (int r = 0; r < 16; ++r) acc0[r] += cf * Cv[r]; }
#define EPI_W011(TT) { int uu = 2 * ((TT) - 48);                                  \
        float cf0 = X10f(uu, eLoc), cf1 = X10f(uu + 1, eLoc);                     \
        _Pragma("unroll") for (int r = 0; r < 16; ++r)                            \
            t011[r & 7] += (r >= 8 ? cf1 : cf0) * Cv[r]; }
#define EPI_W101(TT) { int uu = 2 * ((TT) - 64);                                  \
        float d00 = X11f(0, uu, eLoc), d01 = X11f(1, uu, eLoc), d02 = X11f(2, uu, eLoc);          \
        float d10 = X11f(0, uu + 1, eLoc), d11 = X11f(1, uu + 1, eLoc), d12 = X11f(2, uu + 1, eLoc); \
        _Pragma("unroll") for (int r = 0; r < 16; ++r) {                          \
            int s = r & 7;                                                        \
            t101[0][s] += (r >= 8 ? d10 : d00) * Cv[r];                           \
            t101[1][s] += (r >= 8 ? d11 : d01) * Cv[r];                           \
            t101[2][s] += (r >= 8 ? d12 : d02) * Cv[r]; } }

#define RUN_PHASE(BASE, NT, NEXTT, LAST, EPI)                                     \
    _Pragma("unroll")                                                             \
    for (int t = 0; t < (NT); ++t) {                                              \
        const int cur = (BASE) + t;                                               \
        const int nxt = (t + 1 < (NT)) ? (cur + 1) : (NEXTT);                     \
        f32x16 Cv;                                                                \
        if ((t & 1) == 0) {                                                       \
            if (!(LAST) || (t + 1 < (NT))) LOADA(aQ, nxt);                        \
            MFMA_T(Cv, aP);                                                       \
        } else {                                                                  \
            if (!(LAST) || (t + 1 < (NT))) LOADA(aP, nxt);                        \
            MFMA_T(Cv, aQ);                                                       \
        }                                                                         \
        EPI(cur);                                                                 \
    }

    bf16x8 aP[4], aQ[4];
    LOADA(aP, 0);
    RUN_PHASE(0,  32, 32, false, EPI_W00)   // w00  tiles: u = tile
    RUN_PHASE(32, 16, 48, false, EPI_W110)  // w110 tiles: u = tile-32
    RUN_PHASE(48, 16, 64, false, EPI_W011)  // w011 tiles: u = 2*(tile-48)+{0,1}
    RUN_PHASE(64, 8,  71, true,  EPI_W101)  // w101 tiles: u = 2*(tile-64)+{0,1}

    // ---- output staging: out[e][0..31]=out0 ; out[e][32 + w*3 + k]=out1[w][k] ----
    __syncthreads();  // done with coeff LDS; reuse as staging
    float* OST = smemf;
#pragma unroll
    for (int r = 0; r < 16; ++r) {
        int rv = (r & 3) + 8 * (r >> 2) + 4 * hi;
        OST[eLoc * 80 + rv] = acc0[r];
    }
#pragma unroll
    for (int s = 0; s < 8; ++s) {
        int w = (s & 3) + 8 * (s >> 2) + 4 * hi;
        float b011 = 0.125f * t011[s];   // pw011*ISQRT3 = 1/8
        OST[eLoc * 80 + 32 + w * 3 + 0] = x21a * b011 + s101 * t101[0][s];
        OST[eLoc * 80 + 32 + w * 3 + 1] = x21b * b011 + s101 * t101[1][s];
        OST[eLoc * 80 + 32 + w * 3 + 2] = x21c * b011 + s101 * t101[2][s];
    }
    __syncthreads();
    {
        float4* og = (float4*)(out + (size_t)blockIdx.x * 10240);
        const float4* os = (const float4*)smemf;
        for (int i = tid; i < 2560; i += 256) og[i] = os[i];
    }
}

extern "C" void kernel_launch(void* const* d_in, const int* in_sizes, int n_in,
                              void* d_out, int out_size, void* d_ws, size_t ws_size,
                              hipStream_t stream) {
    const float* fea_in1 = (const float*)d_in[0];
    const float* fea_in2 = (const float*)d_in[1];
    const float* fea_w   = (const float*)d_in[2];
    const float* W1      = (const float*)d_in[3];
    const float* W2      = (const float*)d_in[4];
    __bf16* W2F = (__bf16*)d_ws;
    __bf16* W1F = (__bf16*)((char*)d_ws + (size_t)W2F_ELEMS * 2);

    equiconv_prep<<<(W2F_ELEMS + W1F_ELEMS + 255) / 256, 256, 0, stream>>>(W1, W2, W1F, W2F);
    equiconv_main<<<65536 / 128, 256, 0, stream>>>(fea_in1, fea_in2, fea_w, W2F, W1F, (float*)d_out);
}

// Round 5
// 123.827 us; speedup vs baseline: 1.0813x; 1.0813x over previous
//
#include <hip/hip_runtime.h>
#include <hip/hip_bf16.h>

typedef __attribute__((ext_vector_type(8)))  __bf16 bf16x8;
typedef __attribute__((ext_vector_type(16))) float  f32x16;

#define N_TILES   72          // 2304 / 32
#define W2F_ELEMS (72*4*64*8) // 147456 bf16 (tile = 2048 bf16 = 4096 B)
#define W1F_ELEMS (2*4*64*8)  // 4096 bf16

__device__ __forceinline__ void gload_lds16(const void* g, void* l) {
    __builtin_amdgcn_global_load_lds(
        (const __attribute__((address_space(1))) unsigned int*)g,
        (__attribute__((address_space(3))) unsigned int*)l, 16, 0, 0);
}

__device__ __forceinline__ unsigned pk_bf16(float a, float b) {
    unsigned r;
    asm("v_cvt_pk_bf16_f32 %0, %1, %2" : "=v"(r) : "v"(a), "v"(b));
    return r;
}

// ---------------- prep: pack W2^T/8 and W1^T/8 (bf16) in MFMA A-fragment order ----------------
// A-frag order: [tile][ks][lane][j] holds A[row = 32*tile + (lane&31)][k = 16*ks + 8*(lane>>5) + j]
__global__ __launch_bounds__(256) void equiconv_prep(const float* __restrict__ W1,
                                                     const float* __restrict__ W2,
                                                     __bf16* __restrict__ W1F,
                                                     __bf16* __restrict__ W2F) {
    int idx = blockIdx.x * 256 + threadIdx.x;
    if (idx < W2F_ELEMS) {
        int j  = idx & 7;
        int ln = (idx >> 3) & 63;
        int ks = (idx >> 9) & 3;
        int t  = idx >> 11;
        int m  = 32 * t + (ln & 31);          // W2 column (0..2303)
        int c  = ks * 16 + 8 * (ln >> 5) + j; // W2 row    (0..63)
        W2F[idx] = (__bf16)(W2[c * 2304 + m] * 0.125f);
    } else {
        int i2 = idx - W2F_ELEMS;
        if (i2 < W1F_ELEMS) {
            int j  = i2 & 7;
            int ln = (i2 >> 3) & 63;
            int ks = (i2 >> 9) & 3;
            int mt = i2 >> 11;
            int c  = 32 * mt + (ln & 31);      // W1 output col (0..63)
            int in = ks * 16 + 8 * (ln >> 5) + j;
            W1F[i2] = (__bf16)(W1[in * 64 + c] * 0.125f);
        }
    }
}

// ---------------- main fused kernel: 128 elements / block (4 waves x 32 elems) ----------------
// LDS float layout (14944 floats = 59776 B), all coeff arrays stride-129 (conflict-free):
//   [0     .. 4128 )  X10[u=32][129]
//   [4128  .. 6192 )  CB1[u=16][129]
//   [6192  .. 12384)  X11[(u*3+k)=48][129]
//   [12384 .. 12896)  F2 [e=128][4]
//   [12896 .. 14944)  ASTG: 2 x 2048 bf16 (A-tile double buffer, 4096 B each)
// Output staging (after main loop) reuses [0 .. 10368) floats as [e=128][81].
#define X10f(u, el)    smemf[(u)*129 + (el)]
#define CB1f(u, el)    smemf[4128 + (u)*129 + (el)]
#define X11f(k, u, el) smemf[6192 + ((u)*3 + (k))*129 + (el)]
#define F2f(el, j)     smemf[12384 + (el)*4 + (j)]
#define ASTG_BASE 12896

__global__ __launch_bounds__(256) void equiconv_main(const float* __restrict__ fea_in1,
                                                     const float* __restrict__ fea_in2,
                                                     const float* __restrict__ fea_w,
                                                     const __bf16* __restrict__ W2F,
                                                     const __bf16* __restrict__ W1F,
                                                     float* __restrict__ out) {
    __shared__ __align__(16) float smemf[14944];

    const int tid  = threadIdx.x;
    const int lane = tid & 63;
    const int wv   = tid >> 6;     // wave 0..3
    const int l31  = lane & 31;
    const int hi   = lane >> 5;    // half-wave
    const int eBlk = blockIdx.x * 128;
    const int eLoc = wv * 32 + l31;       // element owned by this lane (0..127)

    // ---- stage fea_in1 -> X10/X11, fea_in2 -> F2 (coalesced reads, conflict-free writes) ----
    for (int i = tid; i < 128 * 80; i += 256) {
        float v = fea_in1[(size_t)eBlk * 80 + i];
        int el = i / 80;
        int j  = i - el * 80;
        if (j < 32) {
            X10f(j, el) = v;
        } else {
            int jj = j - 32;
            int u  = jj / 3;
            int k  = jj - u * 3;
            X11f(k, u, el) = v;
        }
    }
    for (int i = tid; i < 128 * 4; i += 256)
        F2f(i >> 2, i & 3) = fea_in2[(size_t)eBlk * 4 + i];
    __syncthreads();

    // ---- CB1[u][e] = sqrt(1/96) * sum_i x1_1[e][u][i]*x2_1[e][i] ----
    const float c110 = 0.10206207261596577f; // pw110*ISQRT3
    for (int i = tid; i < 16 * 128; i += 256) {
        int u = i >> 7, el = i & 127;
        CB1f(u, el) = c110 * (X11f(0, u, el) * F2f(el, 1) +
                              X11f(1, u, el) * F2f(el, 2) +
                              X11f(2, u, el) * F2f(el, 3));
    }

    // ---- GEMM1: x[c][e] = sum_in (W1[in][c]/8) * feaw[e][in]; h = 1.679*silu(x) ----
    const f32x16 Z16 = {0,0,0,0,0,0,0,0,0,0,0,0,0,0,0,0};
    bf16x8 hfr0, hfr1, hfr2, hfr3;
    {
        bf16x8 bw[4];
        const float* pw = fea_w + (size_t)(eBlk + eLoc) * 64 + hi * 8;
#pragma unroll
        for (int ks = 0; ks < 4; ++ks) {
            float4 u0 = *(const float4*)(pw + ks * 16);
            float4 u1 = *(const float4*)(pw + ks * 16 + 4);
            bf16x8 b;
            b[0] = (__bf16)u0.x; b[1] = (__bf16)u0.y; b[2] = (__bf16)u0.z; b[3] = (__bf16)u0.w;
            b[4] = (__bf16)u1.x; b[5] = (__bf16)u1.y; b[6] = (__bf16)u1.z; b[7] = (__bf16)u1.w;
            bw[ks] = b;
        }
        f32x16 h0 = Z16, h1 = Z16;
#pragma unroll
        for (int ks = 0; ks < 4; ++ks) {
            bf16x8 a0 = *(const bf16x8*)(W1F + (size_t)((0 * 4 + ks) * 64 + lane) * 8);
            h0 = __builtin_amdgcn_mfma_f32_32x32x16_bf16(a0, bw[ks], h0, 0, 0, 0);
            bf16x8 a1 = *(const bf16x8*)(W1F + (size_t)((1 * 4 + ks) * 64 + lane) * 8);
            h1 = __builtin_amdgcn_mfma_f32_32x32x16_bf16(a1, bw[ks], h1, 0, 0, 0);
        }
        // silu of the 32 channels this lane holds: c(r) = (r&3)+8*(r>>2)+4*hi (+32 for h1)
        float sv[32];
#pragma unroll
        for (int r = 0; r < 16; ++r) {
            float x0 = h0[r];
            sv[r]      = 1.679f * x0 / (1.f + __expf(-x0));
            float x1 = h1[r];
            sv[16 + r] = 1.679f * x1 / (1.f + __expf(-x1));
        }
        // In-register B-fragment assembly. Needed: hfr[ks][j] = h[16ks + 8*hi + j][eLoc].
        // Channel blocks (vb = 8*ks covers sv[vb..vb+7] = channels 16ks+{0..3,8..11}+4hi):
        //   hi=0 lane: j0..3 = own sv[vb+0..3] (ch 16ks+0..3),  j4..7 = partner sv[vb+0..3] (ch +4..7)
        //   hi=1 lane: j0..3 = partner sv[vb+4..7] (ch +8..11), j4..7 = own sv[vb+4..7] (ch +12..15)
        uint4 fr[4];
#pragma unroll
        for (int ks = 0; ks < 4; ++ks) {
            const int vb = 8 * ks;
            float oa = hi ? sv[vb + 4] : sv[vb + 0];
            float ob = hi ? sv[vb + 5] : sv[vb + 1];
            float oc = hi ? sv[vb + 6] : sv[vb + 2];
            float od = hi ? sv[vb + 7] : sv[vb + 3];
            float sa = hi ? sv[vb + 0] : sv[vb + 4];
            float sb = hi ? sv[vb + 1] : sv[vb + 5];
            float sc = hi ? sv[vb + 2] : sv[vb + 6];
            float sd = hi ? sv[vb + 3] : sv[vb + 7];
            unsigned o0 = pk_bf16(oa, ob), o1 = pk_bf16(oc, od);
            unsigned s0 = pk_bf16(sa, sb), s1 = pk_bf16(sc, sd);
            unsigned r0 = (unsigned)__shfl_xor((int)s0, 32, 64);
            unsigned r1 = (unsigned)__shfl_xor((int)s1, 32, 64);
            fr[ks].x = hi ? r0 : o0;   // j0,j1
            fr[ks].y = hi ? r1 : o1;   // j2,j3
            fr[ks].z = hi ? o0 : r0;   // j4,j5
            fr[ks].w = hi ? o1 : r1;   // j6,j7
        }
        hfr0 = *(bf16x8*)&fr[0];
        hfr1 = *(bf16x8*)&fr[1];
        hfr2 = *(bf16x8*)&fr[2];
        hfr3 = *(bf16x8*)&fr[3];
    }

    // ---- per-lane coefficient state ----
    const float x20  = F2f(eLoc, 0);
    const float x21a = F2f(eLoc, 1), x21b = F2f(eLoc, 2), x21c = F2f(eLoc, 3);
    const float sA0  = 0.125f * x20;                 // pw00 * x2_0
    const float s101 = 0.17677669529663687f * x20;   // sqrt(1/32) * x2_0

    float acc0[16];
    float t011[8];
    float t101[3][8];
#pragma unroll
    for (int r = 0; r < 16; ++r) acc0[r] = 0.f;
#pragma unroll
    for (int s = 0; s < 8; ++s) { t011[s] = 0.f; t101[0][s] = 0.f; t101[1][s] = 0.f; t101[2][s] = 0.f; }

    const __bf16* ASTG = (const __bf16*)(smemf + ASTG_BASE);
    char* stgb = (char*)(smemf + ASTG_BASE);
    const char* w2b = (const char*)W2F;

    // stage tile T (4096 B) into buffer BUF: 256 threads x one global_load_lds(16B)
#define STAGE(T, BUF) {                                                           \
        const char* _s = w2b + ((size_t)(T) << 12) + wv * 1024 + (lane << 4);     \
        char* _d = stgb + ((BUF) << 12) + wv * 1024;                              \
        gload_lds16(_s, _d); }

    // epilogues: C row rv=(r&3)+8*(r>>2)+4*hi; w_out = rv&15 -> slot s = r&7; u-select = (r>=8)
#define EPI_W00(TT) { float cf = sA0 * X10f((TT), eLoc);                          \
        _Pragma("unroll") for (int r = 0; r < 16; ++r) acc0[r] += cf * Cv[r]; }
#define EPI_W110(TT) { float cf = CB1f((TT) - 32, eLoc);                          \
        _Pragma("unroll") for (int r = 0; r < 16; ++r) acc0[r] += cf * Cv[r]; }
#define EPI_W011(TT) { int uu = 2 * ((TT) - 48);                                  \
        float cf0 = X10f(uu, eLoc), cf1 = X10f(uu + 1, eLoc);                     \
        _Pragma("unroll") for (int r = 0; r < 16; ++r)                            \
            t011[r & 7] += (r >= 8 ? cf1 : cf0) * Cv[r]; }
#define EPI_W101(TT) { int uu = 2 * ((TT) - 64);                                  \
        float d00 = X11f(0, uu, eLoc), d01 = X11f(1, uu, eLoc), d02 = X11f(2, uu, eLoc);          \
        float d10 = X11f(0, uu + 1, eLoc), d11 = X11f(1, uu + 1, eLoc), d12 = X11f(2, uu + 1, eLoc); \
        _Pragma("unroll") for (int r = 0; r < 16; ++r) { int s = r & 7;           \
            t101[0][s] += (r >= 8 ? d10 : d00) * Cv[r];                           \
            t101[1][s] += (r >= 8 ? d11 : d01) * Cv[r];                           \
            t101[2][s] += (r >= 8 ? d12 : d02) * Cv[r]; } }

#define TILE_STEP(T, EPI) {                                                       \
        if ((T) + 1 < N_TILES) STAGE((T) + 1, bufx ^ 1);                          \
        const __bf16* tb = ASTG + (bufx << 11) + (lane << 3);                     \
        bf16x8 a0 = *(const bf16x8*)(tb);                                         \
        bf16x8 a1 = *(const bf16x8*)(tb + 512);                                   \
        bf16x8 a2 = *(const bf16x8*)(tb + 1024);                                  \
        bf16x8 a3 = *(const bf16x8*)(tb + 1536);                                  \
        f32x16 Cv;                                                                \
        Cv = __builtin_amdgcn_mfma_f32_32x32x16_bf16(a0, hfr0, Z16, 0, 0, 0);     \
        Cv = __builtin_amdgcn_mfma_f32_32x32x16_bf16(a1, hfr1, Cv, 0, 0, 0);      \
        Cv = __builtin_amdgcn_mfma_f32_32x32x16_bf16(a2, hfr2, Cv, 0, 0, 0);      \
        Cv = __builtin_amdgcn_mfma_f32_32x32x16_bf16(a3, hfr3, Cv, 0, 0, 0);      \
        EPI(T);                                                                   \
        __syncthreads();                                                          \
        bufx ^= 1; }

    int bufx = 0;
    STAGE(0, 0);
    __syncthreads();   // also covers X10/CB1/X11/F2 writes above (vmcnt drained by barrier)

#pragma unroll 2
    for (int t = 0; t < 32; ++t) TILE_STEP(t, EPI_W00)       // w00  tiles: u = t
#pragma unroll 2
    for (int t = 32; t < 48; ++t) TILE_STEP(t, EPI_W110)     // w110 tiles: u = t-32
#pragma unroll 2
    for (int t = 48; t < 64; ++t) TILE_STEP(t, EPI_W011)     // w011 tiles: u = 2*(t-48)+{0,1}
#pragma unroll 2
    for (int t = 64; t < 72; ++t) TILE_STEP(t, EPI_W101)     // w101 tiles: u = 2*(t-64)+{0,1}

    // ---- output staging (stride 81 = conflict-free): out[e][0..31]=out0 ; [32+w*3+k]=out1 ----
    float* OST = smemf;
#pragma unroll
    for (int r = 0; r < 16; ++r) {
        int rv = (r & 3) + 8 * (r >> 2) + 4 * hi;
        OST[eLoc * 81 + rv] = acc0[r];
    }
#pragma unroll
    for (int s = 0; s < 8; ++s) {
        int w = (s & 3) + 8 * (s >> 2) + 4 * hi;
        float b011 = 0.125f * t011[s];   // pw011*ISQRT3 = 1/8
        OST[eLoc * 81 + 32 + w * 3 + 0] = x21a * b011 + s101 * t101[0][s];
        OST[eLoc * 81 + 32 + w * 3 + 1] = x21b * b011 + s101 * t101[1][s];
        OST[eLoc * 81 + 32 + w * 3 + 2] = x21c * b011 + s101 * t101[2][s];
    }
    __syncthreads();
    {
        float* og = out + (size_t)blockIdx.x * 10240;
        for (int i = tid; i < 10240; i += 256) {
            int el = i / 80;
            int j  = i - el * 80;
            og[i] = OST[el * 81 + j];
        }
    }
}

extern "C" void kernel_launch(void* const* d_in, const int* in_sizes, int n_in,
                              void* d_out, int out_size, void* d_ws, size_t ws_size,
                              hipStream_t stream) {
    const float* fea_in1 = (const float*)d_in[0];
    const float* fea_in2 = (const float*)d_in[1];
    const float* fea_w   = (const float*)d_in[2];
    const float* W1      = (const float*)d_in[3];
    const float* W2      = (const float*)d_in[4];
    __bf16* W2F = (__bf16*)d_ws;
    __bf16* W1F = (__bf16*)((char*)d_ws + (size_t)W2F_ELEMS * 2);

    equiconv_prep<<<(W2F_ELEMS + W1F_ELEMS + 255) / 256, 256, 0, stream>>>(W1, W2, W1F, W2F);
    equiconv_main<<<65536 / 128, 256, 0, stream>>>(fea_in1, fea_in2, fea_w, W2F, W1F, (float*)d_out);
}

// Round 8
// 112.214 us; speedup vs baseline: 1.1933x; 1.1035x over previous
//
#include <hip/hip_runtime.h>
#include <hip/hip_bf16.h>

typedef __attribute__((ext_vector_type(8)))  __bf16 bf16x8;
typedef __attribute__((ext_vector_type(16))) float  f32x16;

#define N_TILES   72          // 2304 / 32
#define W2F_ELEMS (72*4*64*8) // 147456 bf16 (tile = 2048 bf16 = 4096 B)
#define W1F_ELEMS (2*4*64*8)  // 4096 bf16

__device__ __forceinline__ void gload_lds16(const void* g, void* l) {
    __builtin_amdgcn_global_load_lds(
        (const __attribute__((address_space(1))) unsigned int*)g,
        (__attribute__((address_space(3))) unsigned int*)l, 16, 0, 0);
}

__device__ __forceinline__ unsigned pk_bf16(float a, float b) {
    unsigned r;
    asm("v_cvt_pk_bf16_f32 %0, %1, %2" : "=v"(r) : "v"(a), "v"(b));
    return r;
}

// ---------------- prep: pack W2^T/8 and W1^T/8 (bf16) in MFMA A-fragment order ----------------
// A-frag order: [tile][ks][lane][j] holds A[row = 32*tile + (lane&31)][k = 16*ks + 8*(lane>>5) + j]
__global__ __launch_bounds__(256) void equiconv_prep(const float* __restrict__ W1,
                                                     const float* __restrict__ W2,
                                                     __bf16* __restrict__ W1F,
                                                     __bf16* __restrict__ W2F) {
    int idx = blockIdx.x * 256 + threadIdx.x;
    if (idx < W2F_ELEMS) {
        int j  = idx & 7;
        int ln = (idx >> 3) & 63;
        int ks = (idx >> 9) & 3;
        int t  = idx >> 11;
        int m  = 32 * t + (ln & 31);          // W2 column (0..2303)
        int c  = ks * 16 + 8 * (ln >> 5) + j; // W2 row    (0..63)
        W2F[idx] = (__bf16)(W2[c * 2304 + m] * 0.125f);
    } else {
        int i2 = idx - W2F_ELEMS;
        if (i2 < W1F_ELEMS) {
            int j  = i2 & 7;
            int ln = (i2 >> 3) & 63;
            int ks = (i2 >> 9) & 3;
            int mt = i2 >> 11;
            int c  = 32 * mt + (ln & 31);      // W1 output col (0..63)
            int in = ks * 16 + 8 * (ln >> 5) + j;
            W1F[i2] = (__bf16)(W1[in * 64 + c] * 0.125f);
        }
    }
}

// ---------------- main fused kernel: 128 elements / block (4 waves x 32 elems) ----------------
// LDS: 41472 B. Main loop: 8-tile ring in first 32768 B (8 x 4096 B slots).
// After the loop the whole region is reused as output staging [e=128][81] floats.
__global__ __launch_bounds__(256, 2) void equiconv_main(const float* __restrict__ fea_in1,
                                                        const float* __restrict__ fea_in2,
                                                        const float* __restrict__ fea_w,
                                                        const __bf16* __restrict__ W2F,
                                                        const __bf16* __restrict__ W1F,
                                                        float* __restrict__ out) {
    __shared__ __align__(16) float smemf[10368];   // 41472 B
    __bf16* RING = (__bf16*)smemf;
    char*   rgb  = (char*)smemf;
    const char* w2b = (const char*)W2F;

    const int tid  = threadIdx.x;
    const int lane = tid & 63;
    const int wv   = tid >> 6;     // wave 0..3
    const int l31  = lane & 31;
    const int hi   = lane >> 5;    // half-wave
    const int eBlk = blockIdx.x * 128;
    const int eLoc = wv * 32 + l31;       // element owned by this lane (0..127)

    // stage tile T (4096 B) into ring slot T&7: 256 threads x one global_load_lds(16B)
#define STAGE(T) {                                                                \
        const char* _s = w2b + ((size_t)(T) << 12) + wv * 1024 + (lane << 4);     \
        char* _d = rgb + (((T) & 7) << 12) + wv * 1024;                           \
        gload_lds16(_s, _d); }

    // ---- issue ring prefetch of tiles 0..5 immediately (oldest in vmcnt queue) ----
    STAGE(0); STAGE(1); STAGE(2); STAGE(3); STAGE(4); STAGE(5);

    // ---- per-lane coefficient registers: this lane's own element row ----
    const float* r1 = fea_in1 + (size_t)(eBlk + eLoc) * 80;
    float x10[32];
#pragma unroll
    for (int q = 0; q < 8; ++q) {
        float4 v = *(const float4*)(r1 + 4 * q);
        x10[4 * q] = v.x; x10[4 * q + 1] = v.y; x10[4 * q + 2] = v.z; x10[4 * q + 3] = v.w;
    }
    float x11[48];   // x11[u*3+k] = x1_1[e][u][k]
#pragma unroll
    for (int q = 0; q < 12; ++q) {
        float4 v = *(const float4*)(r1 + 32 + 4 * q);
        x11[4 * q] = v.x; x11[4 * q + 1] = v.y; x11[4 * q + 2] = v.z; x11[4 * q + 3] = v.w;
    }
    const float4 f2v = *(const float4*)(fea_in2 + (size_t)(eBlk + eLoc) * 4);

    const float c110 = 0.10206207261596577f; // pw110*ISQRT3 = sqrt(1/96)
    float cb1[16];
#pragma unroll
    for (int u = 0; u < 16; ++u)
        cb1[u] = c110 * (x11[3 * u] * f2v.y + x11[3 * u + 1] * f2v.z + x11[3 * u + 2] * f2v.w);

    // ---- GEMM1: x[c][e] = sum_in (W1[in][c]/8) * feaw[e][in]; h = 1.679*silu(x) ----
    const f32x16 Z16 = {0,0,0,0,0,0,0,0,0,0,0,0,0,0,0,0};
    bf16x8 hfr0, hfr1, hfr2, hfr3;
    {
        bf16x8 bw[4];
        const float* pw = fea_w + (size_t)(eBlk + eLoc) * 64 + hi * 8;
#pragma unroll
        for (int ks = 0; ks < 4; ++ks) {
            float4 u0 = *(const float4*)(pw + ks * 16);
            float4 u1 = *(const float4*)(pw + ks * 16 + 4);
            bf16x8 b;
            b[0] = (__bf16)u0.x; b[1] = (__bf16)u0.y; b[2] = (__bf16)u0.z; b[3] = (__bf16)u0.w;
            b[4] = (__bf16)u1.x; b[5] = (__bf16)u1.y; b[6] = (__bf16)u1.z; b[7] = (__bf16)u1.w;
            bw[ks] = b;
        }
        f32x16 h0 = Z16, h1 = Z16;
#pragma unroll
        for (int ks = 0; ks < 4; ++ks) {
            bf16x8 a0 = *(const bf16x8*)(W1F + (size_t)((0 * 4 + ks) * 64 + lane) * 8);
            h0 = __builtin_amdgcn_mfma_f32_32x32x16_bf16(a0, bw[ks], h0, 0, 0, 0);
            bf16x8 a1 = *(const bf16x8*)(W1F + (size_t)((1 * 4 + ks) * 64 + lane) * 8);
            h1 = __builtin_amdgcn_mfma_f32_32x32x16_bf16(a1, bw[ks], h1, 0, 0, 0);
        }
        // silu of the 32 channels this lane holds: c(r) = (r&3)+8*(r>>2)+4*hi (+32 for h1)
        float sv[32];
#pragma unroll
        for (int r = 0; r < 16; ++r) {
            float x0 = h0[r];
            sv[r]      = 1.679f * x0 / (1.f + __expf(-x0));
            float x1 = h1[r];
            sv[16 + r] = 1.679f * x1 / (1.f + __expf(-x1));
        }
        // In-register B-fragment assembly: hfr[ks][j] = h[16ks + 8*hi + j][eLoc]
        uint4 fr[4];
#pragma unroll
        for (int ks = 0; ks < 4; ++ks) {
            const int vb = 8 * ks;
            float oa = hi ? sv[vb + 4] : sv[vb + 0];
            float ob = hi ? sv[vb + 5] : sv[vb + 1];
            float oc = hi ? sv[vb + 6] : sv[vb + 2];
            float od = hi ? sv[vb + 7] : sv[vb + 3];
            float sa = hi ? sv[vb + 0] : sv[vb + 4];
            float sb = hi ? sv[vb + 1] : sv[vb + 5];
            float sc = hi ? sv[vb + 2] : sv[vb + 6];
            float sd = hi ? sv[vb + 3] : sv[vb + 7];
            unsigned o0 = pk_bf16(oa, ob), o1 = pk_bf16(oc, od);
            unsigned s0 = pk_bf16(sa, sb), s1 = pk_bf16(sc, sd);
            unsigned r0 = (unsigned)__shfl_xor((int)s0, 32, 64);
            unsigned r1 = (unsigned)__shfl_xor((int)s1, 32, 64);
            fr[ks].x = hi ? r0 : o0;   // j0,j1
            fr[ks].y = hi ? r1 : o1;   // j2,j3
            fr[ks].z = hi ? o0 : r0;   // j4,j5
            fr[ks].w = hi ? o1 : r1;   // j6,j7
        }
        hfr0 = *(bf16x8*)&fr[0];
        hfr1 = *(bf16x8*)&fr[1];
        hfr2 = *(bf16x8*)&fr[2];
        hfr3 = *(bf16x8*)&fr[3];
    }

    // ---- accumulators ----
    const float sA0  = 0.125f * f2v.x;               // pw00 * x2_0
    const float s101 = 0.17677669529663687f * f2v.x; // sqrt(1/32) * x2_0
    float acc0[16];
    float t011[8];
    float t101[3][8];
#pragma unroll
    for (int r = 0; r < 16; ++r) acc0[r] = 0.f;
#pragma unroll
    for (int s = 0; s < 8; ++s) { t011[s] = 0.f; t101[0][s] = 0.f; t101[1][s] = 0.f; t101[2][s] = 0.f; }

#define WAITV4 asm volatile("s_waitcnt vmcnt(4)" ::: "memory")
#define WAITV2 asm volatile("s_waitcnt vmcnt(2)" ::: "memory")
#define WAITV0 asm volatile("s_waitcnt vmcnt(0)" ::: "memory")

    // epilogues: C row rv=(r&3)+8*(r>>2)+4*hi; w_out = rv&15 -> slot s = r&7; u-select = (r>=8)
#define EPI_W00(TT) { float cf = sA0 * x10[(TT)];                                 \
        _Pragma("unroll") for (int r = 0; r < 16; ++r) acc0[r] += cf * Cv[r]; }
#define EPI_W110(TT) { float cf = cb1[(TT) - 32];                                 \
        _Pragma("unroll") for (int r = 0; r < 16; ++r) acc0[r] += cf * Cv[r]; }
#define EPI_W011(TT) { const int uu = 2 * ((TT) - 48);                            \
        float cf0 = x10[uu], cf1 = x10[uu + 1];                                   \
        _Pragma("unroll") for (int r = 0; r < 16; ++r)                            \
            t011[r & 7] += (r >= 8 ? cf1 : cf0) * Cv[r]; }
#define EPI_W101(TT) { const int uu = 2 * ((TT) - 64);                            \
        float d00 = x11[3*uu+0],   d01 = x11[3*uu+1],   d02 = x11[3*uu+2];        \
        float d10 = x11[3*uu+3],   d11 = x11[3*uu+4],   d12 = x11[3*uu+5];        \
        _Pragma("unroll") for (int r = 0; r < 16; ++r) { int s = r & 7;           \
            t101[0][s] += (r >= 8 ? d10 : d00) * Cv[r];                           \
            t101[1][s] += (r >= 8 ? d11 : d01) * Cv[r];                           \
            t101[2][s] += (r >= 8 ? d12 : d02) * Cv[r]; } }

#define EPI_ANY(TT) {                                                             \
        if ((TT) < 32)      { EPI_W00(TT) }                                       \
        else if ((TT) < 48) { EPI_W110(TT) }                                      \
        else if ((TT) < 64) { EPI_W011(TT) }                                      \
        else                { EPI_W101(TT) } }

#define DO_TILE(TT) {                                                             \
        const __bf16* tb = RING + (((TT) & 7) << 11) + (lane << 3);               \
        bf16x8 a0 = *(const bf16x8*)(tb);                                         \
        bf16x8 a1 = *(const bf16x8*)(tb + 512);                                   \
        bf16x8 a2 = *(const bf16x8*)(tb + 1024);                                  \
        bf16x8 a3 = *(const bf16x8*)(tb + 1536);                                  \
        f32x16 Cv;                                                                \
        Cv = __builtin_amdgcn_mfma_f32_32x32x16_bf16(a0, hfr0, Z16, 0, 0, 0);     \
        Cv = __builtin_amdgcn_mfma_f32_32x32x16_bf16(a1, hfr1, Cv, 0, 0, 0);      \
        Cv = __builtin_amdgcn_mfma_f32_32x32x16_bf16(a2, hfr2, Cv, 0, 0, 0);      \
        Cv = __builtin_amdgcn_mfma_f32_32x32x16_bf16(a3, hfr3, Cv, 0, 0, 0);      \
        EPI_ANY(TT); }

    // Drain everything once (GEMM1 compute covered the latency of tiles 0..5).
    WAITV0;

    // Main loop: 36 iterations x 2 tiles. Steady-state in-flight <= 6 staged loads;
    // WAITV4 retires the 2 oldest -> tiles 2i,2i+1 resident. Tail: 2 then 0.
#pragma unroll
    for (int i = 0; i < 36; ++i) {
        if (i < 34)       { WAITV4; }
        else if (i == 34) { WAITV2; }
        else              { WAITV0; }
        __builtin_amdgcn_s_barrier();
        __builtin_amdgcn_sched_barrier(0);
        if (2 * i + 6 < N_TILES) { STAGE(2 * i + 6); STAGE(2 * i + 7); }
        DO_TILE(2 * i);
        DO_TILE(2 * i + 1);
    }

    // ---- output staging (stride 81 = conflict-free): out[e][0..31]=out0 ; [32+w*3+k]=out1 ----
    __syncthreads();   // all ring reads done; reuse LDS as staging
    float* OST = smemf;
#pragma unroll
    for (int r = 0; r < 16; ++r) {
        int rv = (r & 3) + 8 * (r >> 2) + 4 * hi;
        OST[eLoc * 81 + rv] = acc0[r];
    }
#pragma unroll
    for (int s = 0; s < 8; ++s) {
        int w = (s & 3) + 8 * (s >> 2) + 4 * hi;
        float b011 = 0.125f * t011[s];   // pw011*ISQRT3 = 1/8
        OST[eLoc * 81 + 32 + w * 3 + 0] = f2v.y * b011 + s101 * t101[0][s];
        OST[eLoc * 81 + 32 + w * 3 + 1] = f2v.z * b011 + s101 * t101[1][s];
        OST[eLoc * 81 + 32 + w * 3 + 2] = f2v.w * b011 + s101 * t101[2][s];
    }
    __syncthreads();
    {
        float* og = out + (size_t)blockIdx.x * 10240;
        for (int i = tid; i < 10240; i += 256) {
            int el = i / 80;
            int j  = i - el * 80;
            og[i] = OST[el * 81 + j];
        }
    }
}

extern "C" void kernel_launch(void* const* d_in, const int* in_sizes, int n_in,
                              void* d_out, int out_size, void* d_ws, size_t ws_size,
                              hipStream_t stream) {
    const float* fea_in1 = (const float*)d_in[0];
    const float* fea_in2 = (const float*)d_in[1];
    const float* fea_w   = (const float*)d_in[2];
    const float* W1      = (const float*)d_in[3];
    const float* W2      = (const float*)d_in[4];
    __bf16* W2F = (__bf16*)d_ws;
    __bf16* W1F = (__bf16*)((char*)d_ws + (size_t)W2F_ELEMS * 2);

    equiconv_prep<<<(W2F_ELEMS + W1F_ELEMS + 255) / 256, 256, 0, stream>>>(W1, W2, W1F, W2F);
    equiconv_main<<<65536 / 128, 256, 0, stream>>>(fea_in1, fea_in2, fea_w, W2F, W1F, (float*)d_out);
}

// Round 9
// 111.006 us; speedup vs baseline: 1.2062x; 1.0109x over previous
//
#include <hip/hip_runtime.h>
#include <hip/hip_bf16.h>

typedef __attribute__((ext_vector_type(8)))  __bf16 bf16x8;
typedef __attribute__((ext_vector_type(16))) float  f32x16;

#define N_TILES   72          // 2304 / 32
#define W2F_ELEMS (72*4*64*8) // 147456 bf16 (tile = 2048 bf16 = 4096 B)
#define W1F_ELEMS (2*4*64*8)  // 4096 bf16

__device__ __forceinline__ void gload_lds16(const void* g, void* l) {
    __builtin_amdgcn_global_load_lds(
        (const __attribute__((address_space(1))) unsigned int*)g,
        (__attribute__((address_space(3))) unsigned int*)l, 16, 0, 0);
}

__device__ __forceinline__ unsigned pk_bf16(float a, float b) {
    unsigned r;
    asm("v_cvt_pk_bf16_f32 %0, %1, %2" : "=v"(r) : "v"(a), "v"(b));
    return r;
}

// ---------------- prep: pack W2^T/8 and W1^T/8 (bf16) in MFMA A-fragment order ----------------
// A-frag order: [tile][ks][lane][j] holds A[row = 32*tile + (lane&31)][k = 16*ks + 8*(lane>>5) + j]
__global__ __launch_bounds__(256) void equiconv_prep(const float* __restrict__ W1,
                                                     const float* __restrict__ W2,
                                                     __bf16* __restrict__ W1F,
                                                     __bf16* __restrict__ W2F) {
    int idx = blockIdx.x * 256 + threadIdx.x;
    if (idx < W2F_ELEMS) {
        int j  = idx & 7;
        int ln = (idx >> 3) & 63;
        int ks = (idx >> 9) & 3;
        int t  = idx >> 11;
        int m  = 32 * t + (ln & 31);          // W2 column (0..2303)
        int c  = ks * 16 + 8 * (ln >> 5) + j; // W2 row    (0..63)
        W2F[idx] = (__bf16)(W2[c * 2304 + m] * 0.125f);
    } else {
        int i2 = idx - W2F_ELEMS;
        if (i2 < W1F_ELEMS) {
            int j  = i2 & 7;
            int ln = (i2 >> 3) & 63;
            int ks = (i2 >> 9) & 3;
            int mt = i2 >> 11;
            int c  = 32 * mt + (ln & 31);      // W1 output col (0..63)
            int in = ks * 16 + 8 * (ln >> 5) + j;
            W1F[i2] = (__bf16)(W1[in * 64 + c] * 0.125f);
        }
    }
}

// ---------------- main fused kernel: 128 elements / block (4 waves x 32 elems) ----------------
// LDS: 41472 B. Main loop: double-buffered 4-tile groups (2 x 16384 B) in first 32 KB.
// After the loop the region is reused as output staging [e=128][81] floats.
__global__ __launch_bounds__(256, 2) void equiconv_main(const float* __restrict__ fea_in1,
                                                        const float* __restrict__ fea_in2,
                                                        const float* __restrict__ fea_w,
                                                        const __bf16* __restrict__ W2F,
                                                        const __bf16* __restrict__ W1F,
                                                        float* __restrict__ out) {
    __shared__ __align__(16) float smemf[10368];   // 41472 B
    __bf16* RING = (__bf16*)smemf;
    char*   rgb  = (char*)smemf;
    const char* w2b = (const char*)W2F;

    const int tid  = threadIdx.x;
    const int lane = tid & 63;
    const int wv   = tid >> 6;     // wave 0..3
    const int l31  = lane & 31;
    const int hi   = lane >> 5;    // half-wave
    const int eBlk = blockIdx.x * 128;
    const int eLoc = wv * 32 + l31;       // element owned by this lane (0..127)

    // stage tile T (4096 B) into ring slot T&7: 256 threads x one global_load_lds(16B)
#define STAGE(T) {                                                                \
        const char* _s = w2b + ((size_t)(T) << 12) + wv * 1024 + (lane << 4);     \
        char* _d = rgb + (((T) & 7) << 12) + wv * 1024;                           \
        gload_lds16(_s, _d); }

    // ---- prefetch first 4-tile group (oldest in vmcnt queue) ----
    STAGE(0); STAGE(1); STAGE(2); STAGE(3);

    // ---- per-lane coefficient registers: this lane's own element row ----
    const float* r1 = fea_in1 + (size_t)(eBlk + eLoc) * 80;
    float x10[32];
#pragma unroll
    for (int q = 0; q < 8; ++q) {
        float4 v = *(const float4*)(r1 + 4 * q);
        x10[4 * q] = v.x; x10[4 * q + 1] = v.y; x10[4 * q + 2] = v.z; x10[4 * q + 3] = v.w;
    }
    float x11[48];   // x11[u*3+k] = x1_1[e][u][k]
#pragma unroll
    for (int q = 0; q < 12; ++q) {
        float4 v = *(const float4*)(r1 + 32 + 4 * q);
        x11[4 * q] = v.x; x11[4 * q + 1] = v.y; x11[4 * q + 2] = v.z; x11[4 * q + 3] = v.w;
    }
    const float4 f2v = *(const float4*)(fea_in2 + (size_t)(eBlk + eLoc) * 4);

    const float c110 = 0.10206207261596577f; // pw110*ISQRT3 = sqrt(1/96)
    float cb1[16];
#pragma unroll
    for (int u = 0; u < 16; ++u)
        cb1[u] = c110 * (x11[3 * u] * f2v.y + x11[3 * u + 1] * f2v.z + x11[3 * u + 2] * f2v.w);

    // ---- GEMM1: x[c][e] = sum_in (W1[in][c]/8) * feaw[e][in]; h = 1.679*silu(x) ----
    const f32x16 Z16 = {0,0,0,0,0,0,0,0,0,0,0,0,0,0,0,0};
    bf16x8 hfr0, hfr1, hfr2, hfr3;
    {
        bf16x8 bw[4];
        const float* pw = fea_w + (size_t)(eBlk + eLoc) * 64 + hi * 8;
#pragma unroll
        for (int ks = 0; ks < 4; ++ks) {
            float4 u0 = *(const float4*)(pw + ks * 16);
            float4 u1 = *(const float4*)(pw + ks * 16 + 4);
            bf16x8 b;
            b[0] = (__bf16)u0.x; b[1] = (__bf16)u0.y; b[2] = (__bf16)u0.z; b[3] = (__bf16)u0.w;
            b[4] = (__bf16)u1.x; b[5] = (__bf16)u1.y; b[6] = (__bf16)u1.z; b[7] = (__bf16)u1.w;
            bw[ks] = b;
        }
        f32x16 h0 = Z16, h1 = Z16;
#pragma unroll
        for (int ks = 0; ks < 4; ++ks) {
            bf16x8 a0 = *(const bf16x8*)(W1F + (size_t)((0 * 4 + ks) * 64 + lane) * 8);
            h0 = __builtin_amdgcn_mfma_f32_32x32x16_bf16(a0, bw[ks], h0, 0, 0, 0);
            bf16x8 a1 = *(const bf16x8*)(W1F + (size_t)((1 * 4 + ks) * 64 + lane) * 8);
            h1 = __builtin_amdgcn_mfma_f32_32x32x16_bf16(a1, bw[ks], h1, 0, 0, 0);
        }
        // silu of the 32 channels this lane holds: c(r) = (r&3)+8*(r>>2)+4*hi (+32 for h1)
        float sv[32];
#pragma unroll
        for (int r = 0; r < 16; ++r) {
            float x0 = h0[r];
            sv[r]      = 1.679f * x0 / (1.f + __expf(-x0));
            float x1 = h1[r];
            sv[16 + r] = 1.679f * x1 / (1.f + __expf(-x1));
        }
        // In-register B-fragment assembly: hfr[ks][j] = h[16ks + 8*hi + j][eLoc]
        uint4 fr[4];
#pragma unroll
        for (int ks = 0; ks < 4; ++ks) {
            const int vb = 8 * ks;
            float oa = hi ? sv[vb + 4] : sv[vb + 0];
            float ob = hi ? sv[vb + 5] : sv[vb + 1];
            float oc = hi ? sv[vb + 6] : sv[vb + 2];
            float od = hi ? sv[vb + 7] : sv[vb + 3];
            float sa = hi ? sv[vb + 0] : sv[vb + 4];
            float sb = hi ? sv[vb + 1] : sv[vb + 5];
            float sc = hi ? sv[vb + 2] : sv[vb + 6];
            float sd = hi ? sv[vb + 3] : sv[vb + 7];
            unsigned o0 = pk_bf16(oa, ob), o1 = pk_bf16(oc, od);
            unsigned s0 = pk_bf16(sa, sb), s1 = pk_bf16(sc, sd);
            unsigned r0 = (unsigned)__shfl_xor((int)s0, 32, 64);
            unsigned r1 = (unsigned)__shfl_xor((int)s1, 32, 64);
            fr[ks].x = hi ? r0 : o0;   // j0,j1
            fr[ks].y = hi ? r1 : o1;   // j2,j3
            fr[ks].z = hi ? o0 : r0;   // j4,j5
            fr[ks].w = hi ? o1 : r1;   // j6,j7
        }
        hfr0 = *(bf16x8*)&fr[0];
        hfr1 = *(bf16x8*)&fr[1];
        hfr2 = *(bf16x8*)&fr[2];
        hfr3 = *(bf16x8*)&fr[3];
    }

    // ---- accumulators ----
    const float sA0  = 0.125f * f2v.x;               // pw00 * x2_0
    const float s101 = 0.17677669529663687f * f2v.x; // sqrt(1/32) * x2_0
    float acc0[16];
    float t011[8];
    float t101[3][8];
#pragma unroll
    for (int r = 0; r < 16; ++r) acc0[r] = 0.f;
#pragma unroll
    for (int s = 0; s < 8; ++s) { t011[s] = 0.f; t101[0][s] = 0.f; t101[1][s] = 0.f; t101[2][s] = 0.f; }

#define WAITV0 asm volatile("s_waitcnt vmcnt(0)" ::: "memory")

    // epilogues: C row rv=(r&3)+8*(r>>2)+4*hi; w_out = rv&15 -> slot s = r&7; u-select = (r>=8)
#define EPI_W00(TT) { float cf = sA0 * x10[(TT)];                                 \
        _Pragma("unroll") for (int r = 0; r < 16; ++r) acc0[r] += cf * Cv[r]; }
#define EPI_W110(TT) { float cf = cb1[(TT) - 32];                                 \
        _Pragma("unroll") for (int r = 0; r < 16; ++r) acc0[r] += cf * Cv[r]; }
#define EPI_W011(TT) { const int uu = 2 * ((TT) - 48);                            \
        float cf0 = x10[uu], cf1 = x10[uu + 1];                                   \
        _Pragma("unroll") for (int r = 0; r < 16; ++r)                            \
            t011[r & 7] += (r >= 8 ? cf1 : cf0) * Cv[r]; }
#define EPI_W101(TT) { const int uu = 2 * ((TT) - 64);                            \
        float d00 = x11[3*uu+0],   d01 = x11[3*uu+1],   d02 = x11[3*uu+2];        \
        float d10 = x11[3*uu+3],   d11 = x11[3*uu+4],   d12 = x11[3*uu+5];        \
        _Pragma("unroll") for (int r = 0; r < 16; ++r) { int s = r & 7;           \
            t101[0][s] += (r >= 8 ? d10 : d00) * Cv[r];                           \
            t101[1][s] += (r >= 8 ? d11 : d01) * Cv[r];                           \
            t101[2][s] += (r >= 8 ? d12 : d02) * Cv[r]; } }

#define EPI_ANY(TT) {                                                             \
        if ((TT) < 32)      { EPI_W00(TT) }                                       \
        else if ((TT) < 48) { EPI_W110(TT) }                                      \
        else if ((TT) < 64) { EPI_W011(TT) }                                      \
        else                { EPI_W101(TT) } }

#define DO_TILE(TT) {                                                             \
        const __bf16* tb = RING + (((TT) & 7) << 11) + (lane << 3);               \
        bf16x8 a0 = *(const bf16x8*)(tb);                                         \
        bf16x8 a1 = *(const bf16x8*)(tb + 512);                                   \
        bf16x8 a2 = *(const bf16x8*)(tb + 1024);                                  \
        bf16x8 a3 = *(const bf16x8*)(tb + 1536);                                  \
        f32x16 Cv;                                                                \
        Cv = __builtin_amdgcn_mfma_f32_32x32x16_bf16(a0, hfr0, Z16, 0, 0, 0);     \
        Cv = __builtin_amdgcn_mfma_f32_32x32x16_bf16(a1, hfr1, Cv, 0, 0, 0);      \
        Cv = __builtin_amdgcn_mfma_f32_32x32x16_bf16(a2, hfr2, Cv, 0, 0, 0);      \
        Cv = __builtin_amdgcn_mfma_f32_32x32x16_bf16(a3, hfr3, Cv, 0, 0, 0);      \
        EPI_ANY(TT); }

    // Main loop: 18 iterations x 4 tiles, double-buffered 16 KB halves.
    // Per iter: wait for this group's 4 staged loads (issued one full iter ago),
    // barrier, stage the NEXT group into the other half, then consume 4 tiles.
#pragma unroll
    for (int i = 0; i < 18; ++i) {
        WAITV0;
        __builtin_amdgcn_s_barrier();
        __builtin_amdgcn_sched_barrier(0);
        if (4 * i + 4 < N_TILES) {
            STAGE(4 * i + 4); STAGE(4 * i + 5); STAGE(4 * i + 6); STAGE(4 * i + 7);
        }
        __builtin_amdgcn_sched_barrier(0);
        DO_TILE(4 * i);
        DO_TILE(4 * i + 1);
        DO_TILE(4 * i + 2);
        DO_TILE(4 * i + 3);
    }

    // ---- output staging (stride 81 = conflict-free): out[e][0..31]=out0 ; [32+w*3+k]=out1 ----
    __syncthreads();   // all ring reads done; reuse LDS as staging
    float* OST = smemf;
#pragma unroll
    for (int r = 0; r < 16; ++r) {
        int rv = (r & 3) + 8 * (r >> 2) + 4 * hi;
        OST[eLoc * 81 + rv] = acc0[r];
    }
#pragma unroll
    for (int s = 0; s < 8; ++s) {
        int w = (s & 3) + 8 * (s >> 2) + 4 * hi;
        float b011 = 0.125f * t011[s];   // pw011*ISQRT3 = 1/8
        OST[eLoc * 81 + 32 + w * 3 + 0] = f2v.y * b011 + s101 * t101[0][s];
        OST[eLoc * 81 + 32 + w * 3 + 1] = f2v.z * b011 + s101 * t101[1][s];
        OST[eLoc * 81 + 32 + w * 3 + 2] = f2v.w * b011 + s101 * t101[2][s];
    }
    __syncthreads();
    {
        float* og = out + (size_t)blockIdx.x * 10240;
        for (int i = tid; i < 10240; i += 256) {
            int el = i / 80;
            int j  = i - el * 80;
            og[i] = OST[el * 81 + j];
        }
    }
}

extern "C" void kernel_launch(void* const* d_in, const int* in_sizes, int n_in,
                              void* d_out, int out_size, void* d_ws, size_t ws_size,
                              hipStream_t stream) {
    const float* fea_in1 = (const float*)d_in[0];
    const float* fea_in2 = (const float*)d_in[1];
    const float* fea_w   = (const float*)d_in[2];
    const float* W1      = (const float*)d_in[3];
    const float* W2      = (const float*)d_in[4];
    __bf16* W2F = (__bf16*)d_ws;
    __bf16* W1F = (__bf16*)((char*)d_ws + (size_t)W2F_ELEMS * 2);

    equiconv_prep<<<(W2F_ELEMS + W1F_ELEMS + 255) / 256, 256, 0, stream>>>(W1, W2, W1F, W2F);
    equiconv_main<<<65536 / 128, 256, 0, stream>>>(fea_in1, fea_in2, fea_w, W2F, W1F, (float*)d_out);
}